// Round 6
// baseline (1249.120 us; speedup 1.0000x reference)
//
#include <hip/hip_runtime.h>
#include <math.h>

#define N_NODES 524288
#define N_EDGES 16777216
#define H1      1024
#define DOUT    128

// bucketed-scatter parameters
#define NB        128              // buckets
#define BSH       12               // log2(nodes per bucket)
#define NODES_PB  4096             // nodes per bucket
#define EPB       8192             // edges per a1 block (LDS-staged)
#define NBLK      (N_EDGES / EPB)  // 2048 a1 blocks
#define CAP       139264           // per-bucket record capacity (131072 avg + 8K slack, mult of 8)
#define PWG       8                // workgroups per bucket in accumulate phases

__device__ __forceinline__ float sigmoid_f(float v) {
    return 1.0f / (1.0f + __expf(-v));
}
__device__ __forceinline__ float softplus_f(float v) {
    return fmaxf(v, 0.0f) + log1pf(__expf(-fabsf(v)));
}
// native no-return LDS float add
__device__ __forceinline__ void lds_fadd(float* p, float v) {
    __hip_atomic_fetch_add(p, v, __ATOMIC_RELAXED, __HIP_MEMORY_SCOPE_WORKGROUP);
}

// ============================ bucketed path =================================

// ---- A1: pure binning, LDS-staged, single interleaved 8B record stream -----
__global__ __launch_bounds__(1024) void a1_stage2(
    const int* __restrict__ ei, const float* __restrict__ ea,
    int* __restrict__ gcur,          // [NB*16] padded cursors
    uint2* __restrict__ urec)        // interleaved {pk,w} records
{
    __shared__ uint2 lrec[EPB];      // 64 KB staging
    __shared__ int cnt[NB];
    __shared__ int scan[NB];
    __shared__ int boff[NB];
    __shared__ int gpos[NB];

    const int c = blockIdx.x, t = threadIdx.x;

    const int vi0 = c * 2048 + t;
    const int vi1 = vi0 + 1024;
    const int4 s4a = ((const int4*)ei)[vi0];
    const int4 s4b = ((const int4*)ei)[vi1];
    const int4 d4a = ((const int4*)(ei + N_EDGES))[vi0];
    const int4 d4b = ((const int4*)(ei + N_EDGES))[vi1];
    const float4 w4a = ((const float4*)ea)[vi0];
    const float4 w4b = ((const float4*)ea)[vi1];
    int srcs[8], dsts[8];
    float ws[8];
    srcs[0]=s4a.x; srcs[1]=s4a.y; srcs[2]=s4a.z; srcs[3]=s4a.w;
    srcs[4]=s4b.x; srcs[5]=s4b.y; srcs[6]=s4b.z; srcs[7]=s4b.w;
    dsts[0]=d4a.x; dsts[1]=d4a.y; dsts[2]=d4a.z; dsts[3]=d4a.w;
    dsts[4]=d4b.x; dsts[5]=d4b.y; dsts[6]=d4b.z; dsts[7]=d4b.w;
    ws[0]=w4a.x; ws[1]=w4a.y; ws[2]=w4a.z; ws[3]=w4a.w;
    ws[4]=w4b.x; ws[5]=w4b.y; ws[6]=w4b.z; ws[7]=w4b.w;

    if (t < NB) cnt[t] = 0;
    __syncthreads();

    int rank[8];
#pragma unroll
    for (int q = 0; q < 8; ++q)
        rank[q] = atomicAdd(&cnt[dsts[q] >> BSH], 1);
    __syncthreads();

    // Hillis-Steele inclusive scan of cnt (128 entries)
    if (t < NB) scan[t] = cnt[t];
    __syncthreads();
    for (int o = 1; o < NB; o <<= 1) {
        int v = 0;
        if (t < NB && t >= o) v = scan[t - o];
        __syncthreads();
        if (t < NB) scan[t] += v;
        __syncthreads();
    }
    if (t < NB) {
        boff[t] = scan[t] - cnt[t];
        gpos[t] = atomicAdd(&gcur[t * 16], cnt[t]);
    }
    __syncthreads();

    // scatter records into LDS, bucket-major
#pragma unroll
    for (int q = 0; q < 8; ++q) {
        const int dst = dsts[q];
        const int b = dst >> BSH;
        lrec[boff[b] + rank[q]] =
            make_uint2(((unsigned int)srcs[q] << 12) |
                       (unsigned int)(dst & (NODES_PB - 1)),
                       __float_as_uint(ws[q]));
    }
    __syncthreads();

    // coalesced flush: wave wv handles buckets wv, wv+16, ... (16 waves)
    const int wv = t >> 6, lane = t & 63;
    const unsigned int* lw = (const unsigned int*)lrec;
    unsigned int* gw = (unsigned int*)urec;
    for (int b = wv; b < NB; b += 16) {
        const int n2   = cnt[b] * 2;            // words in this run
        const int loff = boff[b] * 2;
        const size_t gbase = ((size_t)b * CAP + gpos[b]) * 2;
        for (int i = lane; i < n2; i += 64)
            gw[gbase + i] = lw[loff + i];
    }
}

// ---- B1: msg accumulate in LDS; deg accumulate via global L2 atomics -------
// DS-pipe relief: of the two per-record accumulations, only msg stays on the
// LDS atomic path; deg (just +w) goes to the idle vmem/L2 atomic path.
__global__ __launch_bounds__(512) void b1_accum(
    const uint2* __restrict__ urec, const int* __restrict__ gcur,
    const float* __restrict__ x,
    const float* __restrict__ cg_wf, const float* __restrict__ cg_bf,
    const float* __restrict__ cg_ws, const float* __restrict__ cg_bs,
    float* __restrict__ part1, float* __restrict__ deg_g)
{
    __shared__ float lm[NODES_PB];
    const int b = blockIdx.x / PWG, p = blockIdx.x % PWG;
    for (int i = threadIdx.x; i < NODES_PB; i += 512) lm[i] = 0.0f;
    __syncthreads();
    const float wf0 = cg_wf[0], wf1 = cg_wf[1], wf2 = cg_wf[2], bf = cg_bf[0];
    const float s0c = cg_ws[0], s1c = cg_ws[1], s2c = cg_ws[2], bsc = cg_bs[0];
    const float* xb = x + (size_t)b * NODES_PB;    // bucket's dst slice (16 KB, L1)
    float* degb = deg_g + (size_t)b * NODES_PB;    // bucket's deg slice (L2)
    const int tot = gcur[b * 16];
    const int per = (((tot + PWG - 1) / PWG) + 3) & ~3;   // multiple of 4
    const int s0 = p * per;
    const int s1 = min(tot, s0 + per);
    if (s1 > s0) {
        const uint2* base = urec + (size_t)b * CAP + s0;
        const int n  = s1 - s0;
        const int nq = n >> 2;                    // groups of 4 records
        const uint4* v4 = (const uint4*)base;
        for (int k = (int)threadIdx.x; k < nq; k += 512) {
            const uint4 ra = v4[2 * k];
            const uint4 rb = v4[2 * k + 1];
            const int dl0 = ra.x & (NODES_PB - 1), sr0 = ra.x >> BSH;
            const int dl1 = ra.z & (NODES_PB - 1), sr1 = ra.z >> BSH;
            const int dl2 = rb.x & (NODES_PB - 1), sr2 = rb.x >> BSH;
            const int dl3 = rb.z & (NODES_PB - 1), sr3 = rb.z >> BSH;
            const float w0 = __uint_as_float(ra.y), w1 = __uint_as_float(ra.w);
            const float w2 = __uint_as_float(rb.y), w3 = __uint_as_float(rb.w);
            // issue all 8 gathers before compute
            const float xs0 = x[sr0], xs1 = x[sr1], xs2 = x[sr2], xs3 = x[sr3];
            const float xd0 = xb[dl0], xd1 = xb[dl1], xd2 = xb[dl2], xd3 = xb[dl3];
            const float f0 = fmaf(wf0, xd0, fmaf(wf1, xs0, fmaf(wf2, w0, bf)));
            const float g0 = fmaf(s0c, xd0, fmaf(s1c, xs0, fmaf(s2c, w0, bsc)));
            const float f1 = fmaf(wf0, xd1, fmaf(wf1, xs1, fmaf(wf2, w1, bf)));
            const float g1 = fmaf(s0c, xd1, fmaf(s1c, xs1, fmaf(s2c, w1, bsc)));
            const float f2 = fmaf(wf0, xd2, fmaf(wf1, xs2, fmaf(wf2, w2, bf)));
            const float g2 = fmaf(s0c, xd2, fmaf(s1c, xs2, fmaf(s2c, w2, bsc)));
            const float f3 = fmaf(wf0, xd3, fmaf(wf1, xs3, fmaf(wf2, w3, bf)));
            const float g3 = fmaf(s0c, xd3, fmaf(s1c, xs3, fmaf(s2c, w3, bsc)));
            const float m0 = sigmoid_f(f0) * softplus_f(g0);
            const float m1 = sigmoid_f(f1) * softplus_f(g1);
            const float m2 = sigmoid_f(f2) * softplus_f(g2);
            const float m3 = sigmoid_f(f3) * softplus_f(g3);
            lds_fadd(&lm[dl0], m0);
            lds_fadd(&lm[dl1], m1);
            lds_fadd(&lm[dl2], m2);
            lds_fadd(&lm[dl3], m3);
            unsafeAtomicAdd(&degb[dl0], w0);
            unsafeAtomicAdd(&degb[dl1], w1);
            unsafeAtomicAdd(&degb[dl2], w2);
            unsafeAtomicAdd(&degb[dl3], w3);
        }
        for (int k = (nq << 2) + (int)threadIdx.x; k < n; k += 512) {
            const uint2 v = base[k];
            const int dl = v.x & (NODES_PB - 1);
            const int sr = v.x >> BSH;
            const float w = __uint_as_float(v.y);
            const float xs = x[sr], xd = xb[dl];
            const float f = fmaf(wf0, xd, fmaf(wf1, xs, fmaf(wf2, w, bf)));
            const float g = fmaf(s0c, xd, fmaf(s1c, xs, fmaf(s2c, w, bsc)));
            lds_fadd(&lm[dl], sigmoid_f(f) * softplus_f(g));
            unsafeAtomicAdd(&degb[dl], w);
        }
    }
    __syncthreads();
    float* pm = part1 + (size_t)(b * PWG + p) * NODES_PB;
    for (int k = threadIdx.x; k < NODES_PB; k += 512) pm[k] = lm[k];
}

// ---- C1: combine msg partials + deg (in dinv buffer) → h, dinv, a ----------
__global__ __launch_bounds__(256) void c1_nodemid(
    const float* __restrict__ part1, const float* __restrict__ x,
    const float* __restrict__ gcn_w,
    float* __restrict__ dinv /* in: deg, out: dinv */, float* __restrict__ a)
{
    const int n = blockIdx.x * 256 + threadIdx.x;
    const int b = n >> BSH, dl = n & (NODES_PB - 1);
    const float* pm = part1 + (size_t)b * PWG * NODES_PB + dl;
    float m = 0.0f;
#pragma unroll
    for (int p = 0; p < PWG; ++p) m += pm[(size_t)p * NODES_PB];
    const float d = dinv[n];
    const float h = fmaxf(x[n] + m, 0.0f);
    const float di = (d > 0.0f) ? (1.0f / sqrtf(fmaxf(d, 1e-12f))) : 0.0f;
    dinv[n] = di;
    a[n] = di * h * gcn_w[0];
}

// ---- B2: LDS-accumulate s[dst] += a[src]*w, 4-record batches ---------------
__global__ __launch_bounds__(512) void b2_accum(
    const uint2* __restrict__ urec, const int* __restrict__ gcur,
    const float* __restrict__ a, float* __restrict__ part2)
{
    __shared__ float ls[NODES_PB];
    const int b = blockIdx.x / PWG, p = blockIdx.x % PWG;
    for (int i = threadIdx.x; i < NODES_PB; i += 512) ls[i] = 0.0f;
    __syncthreads();
    const int tot = gcur[b * 16];
    const int per = (((tot + PWG - 1) / PWG) + 3) & ~3;
    const int s0 = p * per;
    const int s1 = min(tot, s0 + per);
    if (s1 > s0) {
        const uint2* base = urec + (size_t)b * CAP + s0;
        const int n  = s1 - s0;
        const int nq = n >> 2;
        const uint4* v4 = (const uint4*)base;
        for (int k = (int)threadIdx.x; k < nq; k += 512) {
            const uint4 ra = v4[2 * k];
            const uint4 rb = v4[2 * k + 1];
            // 4 gathers in flight before any LDS atomic
            const float g0 = a[ra.x >> BSH];
            const float g1 = a[ra.z >> BSH];
            const float g2 = a[rb.x >> BSH];
            const float g3 = a[rb.z >> BSH];
            lds_fadd(&ls[ra.x & (NODES_PB - 1)], g0 * __uint_as_float(ra.y));
            lds_fadd(&ls[ra.z & (NODES_PB - 1)], g1 * __uint_as_float(ra.w));
            lds_fadd(&ls[rb.x & (NODES_PB - 1)], g2 * __uint_as_float(rb.y));
            lds_fadd(&ls[rb.z & (NODES_PB - 1)], g3 * __uint_as_float(rb.w));
        }
        for (int k = (nq << 2) + (int)threadIdx.x; k < n; k += 512) {
            const uint2 v = base[k];
            lds_fadd(&ls[v.x & (NODES_PB - 1)], a[v.x >> BSH] * __uint_as_float(v.y));
        }
    }
    __syncthreads();
    float* ps = part2 + (size_t)(b * PWG + p) * NODES_PB;
    for (int k = threadIdx.x; k < NODES_PB; k += 512) ps[k] = ls[k];
}

// ---- C2: combine partials + node fin ---------------------------------------
__global__ __launch_bounds__(256) void c2_nodefin(
    const float* __restrict__ part2, const float* __restrict__ dinv,
    const float* __restrict__ gcn_b, float* __restrict__ hfin)
{
    const int n = blockIdx.x * 256 + threadIdx.x;
    const int b = n >> BSH, dl = n & (NODES_PB - 1);
    const float* ps = part2 + (size_t)b * PWG * NODES_PB + dl;
    float s = 0.0f;
#pragma unroll
    for (int p = 0; p < PWG; ++p) s += ps[(size_t)p * NODES_PB];
    hfin[n] = fmaxf(fmaf(dinv[n], s, gcn_b[0]), 0.0f);
}

// ============================ fallback (atomic) path ========================

__global__ __launch_bounds__(256) void edge_pass1(
    const int* __restrict__ ei, const float* __restrict__ ea,
    const float* __restrict__ x,
    const float* __restrict__ cg_wf, const float* __restrict__ cg_bf,
    const float* __restrict__ cg_ws, const float* __restrict__ cg_bs,
    float* __restrict__ msg_sum, float* __restrict__ deg)
{
    const float wf0 = cg_wf[0], wf1 = cg_wf[1], wf2 = cg_wf[2], bf = cg_bf[0];
    const float s0 = cg_ws[0], s1 = cg_ws[1], s2 = cg_ws[2], bs = cg_bs[0];
    const int t = blockIdx.x * 256 + threadIdx.x;
    const int4 src4 = ((const int4*)ei)[t];
    const int4 dst4 = ((const int4*)(ei + N_EDGES))[t];
    const float4 w4 = ((const float4*)ea)[t];
    const int* sp = (const int*)&src4;
    const int* dp = (const int*)&dst4;
    const float* wp = (const float*)&w4;
#pragma unroll
    for (int q = 0; q < 4; ++q) {
        const int src = sp[q], dst = dp[q];
        const float w = wp[q];
        const float xs = x[src], xd = x[dst];
        const float f = fmaf(wf0, xd, fmaf(wf1, xs, fmaf(wf2, w, bf)));
        const float s = fmaf(s0, xd, fmaf(s1, xs, fmaf(s2, w, bs)));
        const float msg = sigmoid_f(f) * softplus_f(s);
        unsafeAtomicAdd(&msg_sum[dst], msg);
        unsafeAtomicAdd(&deg[dst], w);
    }
}

__global__ __launch_bounds__(256) void node_mid(
    const float* __restrict__ x, const float* __restrict__ msg_sum,
    float* __restrict__ deg_dinv, float* __restrict__ a,
    const float* __restrict__ gcn_w)
{
    const int i = blockIdx.x * 256 + threadIdx.x;
    const float gw = gcn_w[0];
    const float h = fmaxf(x[i] + msg_sum[i], 0.0f);
    const float d = deg_dinv[i];
    const float dinv = (d > 0.0f) ? (1.0f / sqrtf(fmaxf(d, 1e-12f))) : 0.0f;
    deg_dinv[i] = dinv;
    a[i] = dinv * h * gw;
}

__global__ __launch_bounds__(256) void edge_pass2(
    const int* __restrict__ ei, const float* __restrict__ ea,
    const float* __restrict__ a, float* __restrict__ s)
{
    const int t = blockIdx.x * 256 + threadIdx.x;
    const int4 src4 = ((const int4*)ei)[t];
    const int4 dst4 = ((const int4*)(ei + N_EDGES))[t];
    const float4 w4 = ((const float4*)ea)[t];
    const int* sp = (const int*)&src4;
    const int* dp = (const int*)&dst4;
    const float* wp = (const float*)&w4;
#pragma unroll
    for (int q = 0; q < 4; ++q)
        unsafeAtomicAdd(&s[dp[q]], a[sp[q]] * wp[q]);
}

__global__ __launch_bounds__(256) void node_fin(
    const float* __restrict__ dinv, const float* __restrict__ s,
    const float* __restrict__ gcn_b, float* __restrict__ hfin)
{
    const int i = blockIdx.x * 256 + threadIdx.x;
    hfin[i] = fmaxf(fmaf(dinv[i], s[i], gcn_b[0]), 0.0f);
}

// ============================ dense tail ====================================

__global__ __launch_bounds__(256) void fold_bn(
    const float* __restrict__ l3_w, const float* __restrict__ l3_b,
    const float* __restrict__ g, const float* __restrict__ be,
    float* __restrict__ w3f, float* __restrict__ b3f)
{
    const int idx = blockIdx.x * 256 + threadIdx.x;     // 65536
    const int j = idx >> 6, k = idx & 63;
    const float invs = 1.0f / sqrtf(1.0f + 1e-5f);
    const float sc = g[j] * invs;
    w3f[idx] = l3_w[idx] * sc;
    if (k == 0) b3f[j] = fmaf(l3_b[j], sc, be[j]);
}

__global__ __launch_bounds__(256) void gemm1(
    const float* __restrict__ A, const float* __restrict__ W,
    const float* __restrict__ bias, float* __restrict__ C)
{
    __shared__ float As[64][68];
    __shared__ float Ws[64][68];
    const int bj = blockIdx.x, bi = blockIdx.y;
    const int t = threadIdx.x;
#pragma unroll
    for (int q2 = 0; q2 < 4; ++q2) {
        const int idx = t + 256 * q2;
        const int r = idx >> 4, c = idx & 15;
        const float4 va = *(const float4*)(A + (size_t)(bi * 64 + r) * 64 + c * 4);
        const float4 vw = *(const float4*)(W + (size_t)(bj * 64 + r) * 64 + c * 4);
        As[c*4+0][r] = va.x; As[c*4+1][r] = va.y; As[c*4+2][r] = va.z; As[c*4+3][r] = va.w;
        Ws[c*4+0][r] = vw.x; Ws[c*4+1][r] = vw.y; Ws[c*4+2][r] = vw.z; Ws[c*4+3][r] = vw.w;
    }
    __syncthreads();
    const int tx = t & 15, ty = t >> 4;
    const int i0 = ty * 4, j0 = tx * 4;
    float acc[4][4] = {};
#pragma unroll 16
    for (int k = 0; k < 64; ++k) {
        const float4 av = *(const float4*)&As[k][i0];
        const float4 wv = *(const float4*)&Ws[k][j0];
        const float* ap = (const float*)&av;
        const float* wp = (const float*)&wv;
#pragma unroll
        for (int ii = 0; ii < 4; ++ii)
#pragma unroll
            for (int jj = 0; jj < 4; ++jj)
                acc[ii][jj] = fmaf(ap[ii], wp[jj], acc[ii][jj]);
    }
    const int gj = bj * 64 + j0;
    const float4 bv = *(const float4*)(bias + gj);
#pragma unroll
    for (int ii = 0; ii < 4; ++ii) {
        const int gi = bi * 64 + i0 + ii;
        float4 o;
        o.x = fmaxf(acc[ii][0] + bv.x, 0.0f);
        o.y = fmaxf(acc[ii][1] + bv.y, 0.0f);
        o.z = fmaxf(acc[ii][2] + bv.z, 0.0f);
        o.w = fmaxf(acc[ii][3] + bv.w, 0.0f);
        *(float4*)(C + (size_t)gi * H1 + gj) = o;
    }
}

__global__ __launch_bounds__(256) void gemm2(
    const float* __restrict__ H, const float* __restrict__ W,
    const float* __restrict__ bias, float* __restrict__ O)
{
    __shared__ float Hs[64][36];
    __shared__ float Ws[64][132];
    const int bi = blockIdx.x;
    const int t = threadIdx.x;
    const int tx = t & 31, ty = t >> 5;
    const int i0 = ty * 4, j0 = tx * 4;
    float acc[4][4] = {};
    for (int kc = 0; kc < H1; kc += 64) {
#pragma unroll
        for (int q2 = 0; q2 < 2; ++q2) {
            const int idx = t + 256 * q2;
            const int r = idx >> 4, c = idx & 15;
            const float4 v = *(const float4*)(H + (size_t)(bi * 32 + r) * H1 + kc + c * 4);
            Hs[c*4+0][r] = v.x; Hs[c*4+1][r] = v.y; Hs[c*4+2][r] = v.z; Hs[c*4+3][r] = v.w;
        }
#pragma unroll
        for (int q2 = 0; q2 < 8; ++q2) {
            const int idx = t + 256 * q2;
            const int r = idx >> 4, c = idx & 15;
            const float4 v = *(const float4*)(W + (size_t)r * H1 + kc + c * 4);
            Ws[c*4+0][r] = v.x; Ws[c*4+1][r] = v.y; Ws[c*4+2][r] = v.z; Ws[c*4+3][r] = v.w;
        }
        __syncthreads();
#pragma unroll 16
        for (int k = 0; k < 64; ++k) {
            const float4 hv = *(const float4*)&Hs[k][i0];
            const float4 wv = *(const float4*)&Ws[k][j0];
            const float* hp = (const float*)&hv;
            const float* wp = (const float*)&wv;
#pragma unroll
            for (int ii = 0; ii < 4; ++ii)
#pragma unroll
                for (int jj = 0; jj < 4; ++jj)
                    acc[ii][jj] = fmaf(hp[ii], wp[jj], acc[ii][jj]);
        }
        __syncthreads();
    }
    const float4 bv = *(const float4*)(bias + j0);
#pragma unroll
    for (int ii = 0; ii < 4; ++ii) {
        const int gi = bi * 32 + i0 + ii;
        float4 o;
        o.x = fmaxf(acc[ii][0] + bv.x, 0.0f);
        o.y = fmaxf(acc[ii][1] + bv.y, 0.0f);
        o.z = fmaxf(acc[ii][2] + bv.z, 0.0f);
        o.w = fmaxf(acc[ii][3] + bv.w, 0.0f);
        *(float4*)(O + (size_t)gi * DOUT + j0) = o;
    }
}

// ============================ launch ========================================

extern "C" void kernel_launch(void* const* d_in, const int* in_sizes, int n_in,
                              void* d_out, int out_size, void* d_ws, size_t ws_size,
                              hipStream_t stream) {
    const float* x     = (const float*)d_in[0];
    const float* ea    = (const float*)d_in[1];
    const float* cg_wf = (const float*)d_in[2];
    const float* cg_bf = (const float*)d_in[3];
    const float* cg_ws = (const float*)d_in[4];
    const float* cg_bs = (const float*)d_in[5];
    const float* gcn_w = (const float*)d_in[6];
    const float* gcn_b = (const float*)d_in[7];
    const float* l3_w  = (const float*)d_in[8];
    const float* l3_b  = (const float*)d_in[9];
    const float* bn_g  = (const float*)d_in[10];
    const float* bn_b  = (const float*)d_in[11];
    const float* l4_w  = (const float*)d_in[12];
    const float* l4_b  = (const float*)d_in[13];
    const int*   ei    = (const int*)d_in[14];
    float* out = (float*)d_out;
    char* ws = (char*)d_ws;

    // flat layout, no aliasing (~216 MB total)
    const size_t off_rec  = 0;                                   // 142,606,336
    const size_t off_gcur = off_rec + (size_t)NB * CAP * 8;
    const size_t off_p1   = off_gcur + 8192;
    const size_t off_p2   = off_p1 + (size_t)NB * PWG * NODES_PB * 4;      // msg partials only
    const size_t off_dinv = off_p2 + (size_t)NB * PWG * NODES_PB * 4;
    const size_t off_a    = off_dinv + (size_t)N_NODES * 4;
    const size_t off_hfin = off_a + (size_t)N_NODES * 4;
    const size_t off_h3   = off_hfin + (size_t)N_NODES * 4;
    const size_t off_w3   = off_h3 + (size_t)8192 * H1 * 4;
    const size_t off_b3   = off_w3 + (size_t)H1 * 64 * 4;
    const size_t required = off_b3 + (size_t)H1 * 4;

    if (ws_size >= required) {
        uint2* urec  = (uint2*)(ws + off_rec);
        int*   gcur  = (int*)(ws + off_gcur);
        float* p1    = (float*)(ws + off_p1);
        float* p2    = (float*)(ws + off_p2);
        float* dinv  = (float*)(ws + off_dinv);  // doubles as deg accumulator
        float* a     = (float*)(ws + off_a);
        float* hfin  = (float*)(ws + off_hfin);
        float* h3    = (float*)(ws + off_h3);
        float* w3    = (float*)(ws + off_w3);
        float* b3    = (float*)(ws + off_b3);

        hipMemsetAsync(gcur, 0, 8192, stream);
        hipMemsetAsync(dinv, 0, (size_t)N_NODES * 4, stream);   // deg = 0
        fold_bn<<<256, 256, 0, stream>>>(l3_w, l3_b, bn_g, bn_b, w3, b3);
        a1_stage2<<<NBLK, 1024, 0, stream>>>(ei, ea, gcur, urec);
        b1_accum<<<NB * PWG, 512, 0, stream>>>(urec, gcur, x,
                                               cg_wf, cg_bf, cg_ws, cg_bs, p1, dinv);
        c1_nodemid<<<N_NODES / 256, 256, 0, stream>>>(p1, x, gcn_w, dinv, a);
        b2_accum<<<NB * PWG, 512, 0, stream>>>(urec, gcur, a, p2);
        c2_nodefin<<<N_NODES / 256, 256, 0, stream>>>(p2, dinv, gcn_b, hfin);
        gemm1<<<dim3(16, 128), 256, 0, stream>>>(hfin, w3, b3, h3);
        gemm2<<<256, 256, 0, stream>>>(h3, l4_w, l4_b, out);
    } else {
        // fallback: device-atomic path (fits in ~42 MB)
        float* buf_msg  = (float*)(ws + 0);
        float* buf_deg  = (float*)(ws + (size_t)2097152);
        float* buf_a    = (float*)(ws + (size_t)4194304);
        float* buf_hfin = (float*)(ws + (size_t)6291456);
        float* buf_h3   = (float*)(ws + (size_t)8388608);
        float* buf_w3   = (float*)(ws + (size_t)41943040);
        float* buf_b3   = (float*)(ws + (size_t)42205184);

        hipMemsetAsync(buf_msg, 0, (size_t)N_NODES * 4, stream);
        hipMemsetAsync(buf_deg, 0, (size_t)N_NODES * 4, stream);
        fold_bn<<<256, 256, 0, stream>>>(l3_w, l3_b, bn_g, bn_b, buf_w3, buf_b3);
        edge_pass1<<<N_EDGES / 4 / 256, 256, 0, stream>>>(
            ei, ea, x, cg_wf, cg_bf, cg_ws, cg_bs, buf_msg, buf_deg);
        node_mid<<<N_NODES / 256, 256, 0, stream>>>(x, buf_msg, buf_deg, buf_a, gcn_w);
        hipMemsetAsync(buf_msg, 0, (size_t)N_NODES * 4, stream);
        edge_pass2<<<N_EDGES / 4 / 256, 256, 0, stream>>>(ei, ea, buf_a, buf_msg);
        node_fin<<<N_NODES / 256, 256, 0, stream>>>(buf_deg, buf_msg, gcn_b, buf_hfin);
        gemm1<<<dim3(16, 128), 256, 0, stream>>>(buf_hfin, buf_w3, buf_b3, buf_h3);
        gemm2<<<256, 256, 0, stream>>>(buf_h3, l4_w, l4_b, out);
    }
}

// Round 7
// 666.654 us; speedup vs baseline: 1.8737x; 1.8737x over previous
//
#include <hip/hip_runtime.h>
#include <math.h>

#define N_NODES 524288
#define N_EDGES 16777216
#define H1      1024
#define DOUT    128

// bucketed-scatter parameters
#define NB        128              // buckets
#define BSH       12               // log2(nodes per bucket)
#define NODES_PB  4096             // nodes per bucket
#define EPB       8192             // edges per a1 block (LDS-staged)
#define NBLK      (N_EDGES / EPB)  // 2048 a1 blocks
#define CAP       139264           // per-bucket record capacity (131072 avg + 8K slack, mult of 8)
#define PWG       4                // workgroups per bucket in accumulate phases (halved: amortize per-block fixed cost)

__device__ __forceinline__ float sigmoid_f(float v) {
    return 1.0f / (1.0f + __expf(-v));
}
__device__ __forceinline__ float softplus_f(float v) {
    return fmaxf(v, 0.0f) + log1pf(__expf(-fabsf(v)));
}
// native no-return LDS float add
__device__ __forceinline__ void lds_fadd(float* p, float v) {
    __hip_atomic_fetch_add(p, v, __ATOMIC_RELAXED, __HIP_MEMORY_SCOPE_WORKGROUP);
}

// ============================ bucketed path =================================

// ---- A1: pure binning, LDS-staged, single interleaved 8B record stream -----
__global__ __launch_bounds__(1024) void a1_stage2(
    const int* __restrict__ ei, const float* __restrict__ ea,
    int* __restrict__ gcur,          // [NB*16] padded cursors
    uint2* __restrict__ urec)        // interleaved {pk,w} records
{
    __shared__ uint2 lrec[EPB];      // 64 KB staging
    __shared__ int cnt[NB];
    __shared__ int scan[NB];
    __shared__ int boff[NB];
    __shared__ int gpos[NB];

    const int c = blockIdx.x, t = threadIdx.x;

    const int vi0 = c * 2048 + t;
    const int vi1 = vi0 + 1024;
    const int4 s4a = ((const int4*)ei)[vi0];
    const int4 s4b = ((const int4*)ei)[vi1];
    const int4 d4a = ((const int4*)(ei + N_EDGES))[vi0];
    const int4 d4b = ((const int4*)(ei + N_EDGES))[vi1];
    const float4 w4a = ((const float4*)ea)[vi0];
    const float4 w4b = ((const float4*)ea)[vi1];
    int srcs[8], dsts[8];
    float ws[8];
    srcs[0]=s4a.x; srcs[1]=s4a.y; srcs[2]=s4a.z; srcs[3]=s4a.w;
    srcs[4]=s4b.x; srcs[5]=s4b.y; srcs[6]=s4b.z; srcs[7]=s4b.w;
    dsts[0]=d4a.x; dsts[1]=d4a.y; dsts[2]=d4a.z; dsts[3]=d4a.w;
    dsts[4]=d4b.x; dsts[5]=d4b.y; dsts[6]=d4b.z; dsts[7]=d4b.w;
    ws[0]=w4a.x; ws[1]=w4a.y; ws[2]=w4a.z; ws[3]=w4a.w;
    ws[4]=w4b.x; ws[5]=w4b.y; ws[6]=w4b.z; ws[7]=w4b.w;

    if (t < NB) cnt[t] = 0;
    __syncthreads();

    int rank[8];
#pragma unroll
    for (int q = 0; q < 8; ++q)
        rank[q] = atomicAdd(&cnt[dsts[q] >> BSH], 1);
    __syncthreads();

    // Hillis-Steele inclusive scan of cnt (128 entries)
    if (t < NB) scan[t] = cnt[t];
    __syncthreads();
    for (int o = 1; o < NB; o <<= 1) {
        int v = 0;
        if (t < NB && t >= o) v = scan[t - o];
        __syncthreads();
        if (t < NB) scan[t] += v;
        __syncthreads();
    }
    if (t < NB) {
        boff[t] = scan[t] - cnt[t];
        gpos[t] = atomicAdd(&gcur[t * 16], cnt[t]);
    }
    __syncthreads();

    // scatter records into LDS, bucket-major
#pragma unroll
    for (int q = 0; q < 8; ++q) {
        const int dst = dsts[q];
        const int b = dst >> BSH;
        lrec[boff[b] + rank[q]] =
            make_uint2(((unsigned int)srcs[q] << 12) |
                       (unsigned int)(dst & (NODES_PB - 1)),
                       __float_as_uint(ws[q]));
    }
    __syncthreads();

    // coalesced flush: wave wv handles buckets wv, wv+16, ... (16 waves)
    const int wv = t >> 6, lane = t & 63;
    const unsigned int* lw = (const unsigned int*)lrec;
    unsigned int* gw = (unsigned int*)urec;
    for (int b = wv; b < NB; b += 16) {
        const int n2   = cnt[b] * 2;            // words in this run
        const int loff = boff[b] * 2;
        const size_t gbase = ((size_t)b * CAP + gpos[b]) * 2;
        for (int i = lane; i < n2; i += 64)
            gw[gbase + i] = lw[loff + i];
    }
}

// ---- B1: recompute-msg accumulate, 4-record batched loads+gathers ----------
__global__ __launch_bounds__(512) void b1_accum(
    const uint2* __restrict__ urec, const int* __restrict__ gcur,
    const float* __restrict__ x,
    const float* __restrict__ cg_wf, const float* __restrict__ cg_bf,
    const float* __restrict__ cg_ws, const float* __restrict__ cg_bs,
    float* __restrict__ part1)
{
    __shared__ float lm[NODES_PB];
    __shared__ float ld[NODES_PB];
    const int b = blockIdx.x / PWG, p = blockIdx.x % PWG;
    for (int i = threadIdx.x; i < NODES_PB; i += 512) { lm[i] = 0.0f; ld[i] = 0.0f; }
    __syncthreads();
    const float wf0 = cg_wf[0], wf1 = cg_wf[1], wf2 = cg_wf[2], bf = cg_bf[0];
    const float s0c = cg_ws[0], s1c = cg_ws[1], s2c = cg_ws[2], bsc = cg_bs[0];
    const float* xb = x + (size_t)b * NODES_PB;   // bucket's dst slice (16 KB, L1)
    const int tot = gcur[b * 16];
    const int per = (((tot + PWG - 1) / PWG) + 3) & ~3;   // multiple of 4
    const int s0 = p * per;
    const int s1 = min(tot, s0 + per);
    if (s1 > s0) {
        const uint2* base = urec + (size_t)b * CAP + s0;
        const int n  = s1 - s0;
        const int nq = n >> 2;                    // groups of 4 records
        const uint4* v4 = (const uint4*)base;
        for (int k = (int)threadIdx.x; k < nq; k += 512) {
            const uint4 ra = v4[2 * k];
            const uint4 rb = v4[2 * k + 1];
            const int dl0 = ra.x & (NODES_PB - 1), sr0 = ra.x >> BSH;
            const int dl1 = ra.z & (NODES_PB - 1), sr1 = ra.z >> BSH;
            const int dl2 = rb.x & (NODES_PB - 1), sr2 = rb.x >> BSH;
            const int dl3 = rb.z & (NODES_PB - 1), sr3 = rb.z >> BSH;
            const float w0 = __uint_as_float(ra.y), w1 = __uint_as_float(ra.w);
            const float w2 = __uint_as_float(rb.y), w3 = __uint_as_float(rb.w);
            // issue all 8 gathers before compute
            const float xs0 = x[sr0], xs1 = x[sr1], xs2 = x[sr2], xs3 = x[sr3];
            const float xd0 = xb[dl0], xd1 = xb[dl1], xd2 = xb[dl2], xd3 = xb[dl3];
            const float f0 = fmaf(wf0, xd0, fmaf(wf1, xs0, fmaf(wf2, w0, bf)));
            const float g0 = fmaf(s0c, xd0, fmaf(s1c, xs0, fmaf(s2c, w0, bsc)));
            const float f1 = fmaf(wf0, xd1, fmaf(wf1, xs1, fmaf(wf2, w1, bf)));
            const float g1 = fmaf(s0c, xd1, fmaf(s1c, xs1, fmaf(s2c, w1, bsc)));
            const float f2 = fmaf(wf0, xd2, fmaf(wf1, xs2, fmaf(wf2, w2, bf)));
            const float g2 = fmaf(s0c, xd2, fmaf(s1c, xs2, fmaf(s2c, w2, bsc)));
            const float f3 = fmaf(wf0, xd3, fmaf(wf1, xs3, fmaf(wf2, w3, bf)));
            const float g3 = fmaf(s0c, xd3, fmaf(s1c, xs3, fmaf(s2c, w3, bsc)));
            const float m0 = sigmoid_f(f0) * softplus_f(g0);
            const float m1 = sigmoid_f(f1) * softplus_f(g1);
            const float m2 = sigmoid_f(f2) * softplus_f(g2);
            const float m3 = sigmoid_f(f3) * softplus_f(g3);
            lds_fadd(&lm[dl0], m0);
            lds_fadd(&ld[dl0], w0);
            lds_fadd(&lm[dl1], m1);
            lds_fadd(&ld[dl1], w1);
            lds_fadd(&lm[dl2], m2);
            lds_fadd(&ld[dl2], w2);
            lds_fadd(&lm[dl3], m3);
            lds_fadd(&ld[dl3], w3);
        }
        for (int k = (nq << 2) + (int)threadIdx.x; k < n; k += 512) {
            const uint2 v = base[k];
            const int dl = v.x & (NODES_PB - 1);
            const int sr = v.x >> BSH;
            const float w = __uint_as_float(v.y);
            const float xs = x[sr], xd = xb[dl];
            const float f = fmaf(wf0, xd, fmaf(wf1, xs, fmaf(wf2, w, bf)));
            const float g = fmaf(s0c, xd, fmaf(s1c, xs, fmaf(s2c, w, bsc)));
            lds_fadd(&lm[dl], sigmoid_f(f) * softplus_f(g));
            lds_fadd(&ld[dl], w);
        }
    }
    __syncthreads();
    float* pm = part1 + (size_t)(b * PWG + p) * NODES_PB;
    float* pd = part1 + (size_t)NB * PWG * NODES_PB + (size_t)(b * PWG + p) * NODES_PB;
    for (int k = threadIdx.x; k < NODES_PB; k += 512) { pm[k] = lm[k]; pd[k] = ld[k]; }
}

// ---- C1: combine partials + node mid (h, dinv, a) --------------------------
__global__ __launch_bounds__(256) void c1_nodemid(
    const float* __restrict__ part1, const float* __restrict__ x,
    const float* __restrict__ gcn_w,
    float* __restrict__ dinv, float* __restrict__ a)
{
    const int n = blockIdx.x * 256 + threadIdx.x;
    const int b = n >> BSH, dl = n & (NODES_PB - 1);
    const float* pm = part1 + (size_t)b * PWG * NODES_PB + dl;
    const float* pd = part1 + (size_t)NB * PWG * NODES_PB + (size_t)b * PWG * NODES_PB + dl;
    float m = 0.0f, d = 0.0f;
#pragma unroll
    for (int p = 0; p < PWG; ++p) {
        m += pm[(size_t)p * NODES_PB];
        d += pd[(size_t)p * NODES_PB];
    }
    const float h = fmaxf(x[n] + m, 0.0f);
    const float di = (d > 0.0f) ? (1.0f / sqrtf(fmaxf(d, 1e-12f))) : 0.0f;
    dinv[n] = di;
    a[n] = di * h * gcn_w[0];
}

// ---- B2: LDS-accumulate s[dst] += a[src]*w, 4-record batches ---------------
__global__ __launch_bounds__(512) void b2_accum(
    const uint2* __restrict__ urec, const int* __restrict__ gcur,
    const float* __restrict__ a, float* __restrict__ part2)
{
    __shared__ float ls[NODES_PB];
    const int b = blockIdx.x / PWG, p = blockIdx.x % PWG;
    for (int i = threadIdx.x; i < NODES_PB; i += 512) ls[i] = 0.0f;
    __syncthreads();
    const int tot = gcur[b * 16];
    const int per = (((tot + PWG - 1) / PWG) + 3) & ~3;
    const int s0 = p * per;
    const int s1 = min(tot, s0 + per);
    if (s1 > s0) {
        const uint2* base = urec + (size_t)b * CAP + s0;
        const int n  = s1 - s0;
        const int nq = n >> 2;
        const uint4* v4 = (const uint4*)base;
        for (int k = (int)threadIdx.x; k < nq; k += 512) {
            const uint4 ra = v4[2 * k];
            const uint4 rb = v4[2 * k + 1];
            // 4 gathers in flight before any LDS atomic
            const float g0 = a[ra.x >> BSH];
            const float g1 = a[ra.z >> BSH];
            const float g2 = a[rb.x >> BSH];
            const float g3 = a[rb.z >> BSH];
            lds_fadd(&ls[ra.x & (NODES_PB - 1)], g0 * __uint_as_float(ra.y));
            lds_fadd(&ls[ra.z & (NODES_PB - 1)], g1 * __uint_as_float(ra.w));
            lds_fadd(&ls[rb.x & (NODES_PB - 1)], g2 * __uint_as_float(rb.y));
            lds_fadd(&ls[rb.z & (NODES_PB - 1)], g3 * __uint_as_float(rb.w));
        }
        for (int k = (nq << 2) + (int)threadIdx.x; k < n; k += 512) {
            const uint2 v = base[k];
            lds_fadd(&ls[v.x & (NODES_PB - 1)], a[v.x >> BSH] * __uint_as_float(v.y));
        }
    }
    __syncthreads();
    float* ps = part2 + (size_t)(b * PWG + p) * NODES_PB;
    for (int k = threadIdx.x; k < NODES_PB; k += 512) ps[k] = ls[k];
}

// ---- C2: combine partials + node fin ---------------------------------------
__global__ __launch_bounds__(256) void c2_nodefin(
    const float* __restrict__ part2, const float* __restrict__ dinv,
    const float* __restrict__ gcn_b, float* __restrict__ hfin)
{
    const int n = blockIdx.x * 256 + threadIdx.x;
    const int b = n >> BSH, dl = n & (NODES_PB - 1);
    const float* ps = part2 + (size_t)b * PWG * NODES_PB + dl;
    float s = 0.0f;
#pragma unroll
    for (int p = 0; p < PWG; ++p) s += ps[(size_t)p * NODES_PB];
    hfin[n] = fmaxf(fmaf(dinv[n], s, gcn_b[0]), 0.0f);
}

// ============================ fallback (atomic) path ========================

__global__ __launch_bounds__(256) void edge_pass1(
    const int* __restrict__ ei, const float* __restrict__ ea,
    const float* __restrict__ x,
    const float* __restrict__ cg_wf, const float* __restrict__ cg_bf,
    const float* __restrict__ cg_ws, const float* __restrict__ cg_bs,
    float* __restrict__ msg_sum, float* __restrict__ deg)
{
    const float wf0 = cg_wf[0], wf1 = cg_wf[1], wf2 = cg_wf[2], bf = cg_bf[0];
    const float s0 = cg_ws[0], s1 = cg_ws[1], s2 = cg_ws[2], bs = cg_bs[0];
    const int t = blockIdx.x * 256 + threadIdx.x;
    const int4 src4 = ((const int4*)ei)[t];
    const int4 dst4 = ((const int4*)(ei + N_EDGES))[t];
    const float4 w4 = ((const float4*)ea)[t];
    const int* sp = (const int*)&src4;
    const int* dp = (const int*)&dst4;
    const float* wp = (const float*)&w4;
#pragma unroll
    for (int q = 0; q < 4; ++q) {
        const int src = sp[q], dst = dp[q];
        const float w = wp[q];
        const float xs = x[src], xd = x[dst];
        const float f = fmaf(wf0, xd, fmaf(wf1, xs, fmaf(wf2, w, bf)));
        const float s = fmaf(s0, xd, fmaf(s1, xs, fmaf(s2, w, bs)));
        const float msg = sigmoid_f(f) * softplus_f(s);
        unsafeAtomicAdd(&msg_sum[dst], msg);
        unsafeAtomicAdd(&deg[dst], w);
    }
}

__global__ __launch_bounds__(256) void node_mid(
    const float* __restrict__ x, const float* __restrict__ msg_sum,
    float* __restrict__ deg_dinv, float* __restrict__ a,
    const float* __restrict__ gcn_w)
{
    const int i = blockIdx.x * 256 + threadIdx.x;
    const float gw = gcn_w[0];
    const float h = fmaxf(x[i] + msg_sum[i], 0.0f);
    const float d = deg_dinv[i];
    const float dinv = (d > 0.0f) ? (1.0f / sqrtf(fmaxf(d, 1e-12f))) : 0.0f;
    deg_dinv[i] = dinv;
    a[i] = dinv * h * gw;
}

__global__ __launch_bounds__(256) void edge_pass2(
    const int* __restrict__ ei, const float* __restrict__ ea,
    const float* __restrict__ a, float* __restrict__ s)
{
    const int t = blockIdx.x * 256 + threadIdx.x;
    const int4 src4 = ((const int4*)ei)[t];
    const int4 dst4 = ((const int4*)(ei + N_EDGES))[t];
    const float4 w4 = ((const float4*)ea)[t];
    const int* sp = (const int*)&src4;
    const int* dp = (const int*)&dst4;
    const float* wp = (const float*)&w4;
#pragma unroll
    for (int q = 0; q < 4; ++q)
        unsafeAtomicAdd(&s[dp[q]], a[sp[q]] * wp[q]);
}

__global__ __launch_bounds__(256) void node_fin(
    const float* __restrict__ dinv, const float* __restrict__ s,
    const float* __restrict__ gcn_b, float* __restrict__ hfin)
{
    const int i = blockIdx.x * 256 + threadIdx.x;
    hfin[i] = fmaxf(fmaf(dinv[i], s[i], gcn_b[0]), 0.0f);
}

// ============================ dense tail ====================================

__global__ __launch_bounds__(256) void fold_bn(
    const float* __restrict__ l3_w, const float* __restrict__ l3_b,
    const float* __restrict__ g, const float* __restrict__ be,
    float* __restrict__ w3f, float* __restrict__ b3f)
{
    const int idx = blockIdx.x * 256 + threadIdx.x;     // 65536
    const int j = idx >> 6, k = idx & 63;
    const float invs = 1.0f / sqrtf(1.0f + 1e-5f);
    const float sc = g[j] * invs;
    w3f[idx] = l3_w[idx] * sc;
    if (k == 0) b3f[j] = fmaf(l3_b[j], sc, be[j]);
}

__global__ __launch_bounds__(256) void gemm1(
    const float* __restrict__ A, const float* __restrict__ W,
    const float* __restrict__ bias, float* __restrict__ C)
{
    __shared__ float As[64][68];
    __shared__ float Ws[64][68];
    const int bj = blockIdx.x, bi = blockIdx.y;
    const int t = threadIdx.x;
#pragma unroll
    for (int q2 = 0; q2 < 4; ++q2) {
        const int idx = t + 256 * q2;
        const int r = idx >> 4, c = idx & 15;
        const float4 va = *(const float4*)(A + (size_t)(bi * 64 + r) * 64 + c * 4);
        const float4 vw = *(const float4*)(W + (size_t)(bj * 64 + r) * 64 + c * 4);
        As[c*4+0][r] = va.x; As[c*4+1][r] = va.y; As[c*4+2][r] = va.z; As[c*4+3][r] = va.w;
        Ws[c*4+0][r] = vw.x; Ws[c*4+1][r] = vw.y; Ws[c*4+2][r] = vw.z; Ws[c*4+3][r] = vw.w;
    }
    __syncthreads();
    const int tx = t & 15, ty = t >> 4;
    const int i0 = ty * 4, j0 = tx * 4;
    float acc[4][4] = {};
#pragma unroll 16
    for (int k = 0; k < 64; ++k) {
        const float4 av = *(const float4*)&As[k][i0];
        const float4 wv = *(const float4*)&Ws[k][j0];
        const float* ap = (const float*)&av;
        const float* wp = (const float*)&wv;
#pragma unroll
        for (int ii = 0; ii < 4; ++ii)
#pragma unroll
            for (int jj = 0; jj < 4; ++jj)
                acc[ii][jj] = fmaf(ap[ii], wp[jj], acc[ii][jj]);
    }
    const int gj = bj * 64 + j0;
    const float4 bv = *(const float4*)(bias + gj);
#pragma unroll
    for (int ii = 0; ii < 4; ++ii) {
        const int gi = bi * 64 + i0 + ii;
        float4 o;
        o.x = fmaxf(acc[ii][0] + bv.x, 0.0f);
        o.y = fmaxf(acc[ii][1] + bv.y, 0.0f);
        o.z = fmaxf(acc[ii][2] + bv.z, 0.0f);
        o.w = fmaxf(acc[ii][3] + bv.w, 0.0f);
        *(float4*)(C + (size_t)gi * H1 + gj) = o;
    }
}

__global__ __launch_bounds__(256) void gemm2(
    const float* __restrict__ H, const float* __restrict__ W,
    const float* __restrict__ bias, float* __restrict__ O)
{
    __shared__ float Hs[64][36];
    __shared__ float Ws[64][132];
    const int bi = blockIdx.x;
    const int t = threadIdx.x;
    const int tx = t & 31, ty = t >> 5;
    const int i0 = ty * 4, j0 = tx * 4;
    float acc[4][4] = {};
    for (int kc = 0; kc < H1; kc += 64) {
#pragma unroll
        for (int q2 = 0; q2 < 2; ++q2) {
            const int idx = t + 256 * q2;
            const int r = idx >> 4, c = idx & 15;
            const float4 v = *(const float4*)(H + (size_t)(bi * 32 + r) * H1 + kc + c * 4);
            Hs[c*4+0][r] = v.x; Hs[c*4+1][r] = v.y; Hs[c*4+2][r] = v.z; Hs[c*4+3][r] = v.w;
        }
#pragma unroll
        for (int q2 = 0; q2 < 8; ++q2) {
            const int idx = t + 256 * q2;
            const int r = idx >> 4, c = idx & 15;
            const float4 v = *(const float4*)(W + (size_t)r * H1 + kc + c * 4);
            Ws[c*4+0][r] = v.x; Ws[c*4+1][r] = v.y; Ws[c*4+2][r] = v.z; Ws[c*4+3][r] = v.w;
        }
        __syncthreads();
#pragma unroll 16
        for (int k = 0; k < 64; ++k) {
            const float4 hv = *(const float4*)&Hs[k][i0];
            const float4 wv = *(const float4*)&Ws[k][j0];
            const float* hp = (const float*)&hv;
            const float* wp = (const float*)&wv;
#pragma unroll
            for (int ii = 0; ii < 4; ++ii)
#pragma unroll
                for (int jj = 0; jj < 4; ++jj)
                    acc[ii][jj] = fmaf(hp[ii], wp[jj], acc[ii][jj]);
        }
        __syncthreads();
    }
    const float4 bv = *(const float4*)(bias + j0);
#pragma unroll
    for (int ii = 0; ii < 4; ++ii) {
        const int gi = bi * 32 + i0 + ii;
        float4 o;
        o.x = fmaxf(acc[ii][0] + bv.x, 0.0f);
        o.y = fmaxf(acc[ii][1] + bv.y, 0.0f);
        o.z = fmaxf(acc[ii][2] + bv.z, 0.0f);
        o.w = fmaxf(acc[ii][3] + bv.w, 0.0f);
        *(float4*)(O + (size_t)gi * DOUT + j0) = o;
    }
}

// ============================ launch ========================================

extern "C" void kernel_launch(void* const* d_in, const int* in_sizes, int n_in,
                              void* d_out, int out_size, void* d_ws, size_t ws_size,
                              hipStream_t stream) {
    const float* x     = (const float*)d_in[0];
    const float* ea    = (const float*)d_in[1];
    const float* cg_wf = (const float*)d_in[2];
    const float* cg_bf = (const float*)d_in[3];
    const float* cg_ws = (const float*)d_in[4];
    const float* cg_bs = (const float*)d_in[5];
    const float* gcn_w = (const float*)d_in[6];
    const float* gcn_b = (const float*)d_in[7];
    const float* l3_w  = (const float*)d_in[8];
    const float* l3_b  = (const float*)d_in[9];
    const float* bn_g  = (const float*)d_in[10];
    const float* bn_b  = (const float*)d_in[11];
    const float* l4_w  = (const float*)d_in[12];
    const float* l4_b  = (const float*)d_in[13];
    const int*   ei    = (const int*)d_in[14];
    float* out = (float*)d_out;
    char* ws = (char*)d_ws;

    // flat layout, no aliasing (~208 MB total)
    const size_t off_rec  = 0;                                   // 142,606,336
    const size_t off_gcur = off_rec + (size_t)NB * CAP * 8;
    const size_t off_p1   = off_gcur + 8192;
    const size_t off_p2   = off_p1 + (size_t)NB * PWG * NODES_PB * 2 * 4;  // 16.8 MB
    const size_t off_dinv = off_p2 + (size_t)NB * PWG * NODES_PB * 4;      // 8.4 MB
    const size_t off_a    = off_dinv + (size_t)N_NODES * 4;
    const size_t off_hfin = off_a + (size_t)N_NODES * 4;
    const size_t off_h3   = off_hfin + (size_t)N_NODES * 4;
    const size_t off_w3   = off_h3 + (size_t)8192 * H1 * 4;
    const size_t off_b3   = off_w3 + (size_t)H1 * 64 * 4;
    const size_t required = off_b3 + (size_t)H1 * 4;

    if (ws_size >= required) {
        uint2* urec  = (uint2*)(ws + off_rec);
        int*   gcur  = (int*)(ws + off_gcur);
        float* p1    = (float*)(ws + off_p1);
        float* p2    = (float*)(ws + off_p2);
        float* dinv  = (float*)(ws + off_dinv);
        float* a     = (float*)(ws + off_a);
        float* hfin  = (float*)(ws + off_hfin);
        float* h3    = (float*)(ws + off_h3);
        float* w3    = (float*)(ws + off_w3);
        float* b3    = (float*)(ws + off_b3);

        hipMemsetAsync(gcur, 0, 8192, stream);
        fold_bn<<<256, 256, 0, stream>>>(l3_w, l3_b, bn_g, bn_b, w3, b3);
        a1_stage2<<<NBLK, 1024, 0, stream>>>(ei, ea, gcur, urec);
        b1_accum<<<NB * PWG, 512, 0, stream>>>(urec, gcur, x,
                                               cg_wf, cg_bf, cg_ws, cg_bs, p1);
        c1_nodemid<<<N_NODES / 256, 256, 0, stream>>>(p1, x, gcn_w, dinv, a);
        b2_accum<<<NB * PWG, 512, 0, stream>>>(urec, gcur, a, p2);
        c2_nodefin<<<N_NODES / 256, 256, 0, stream>>>(p2, dinv, gcn_b, hfin);
        gemm1<<<dim3(16, 128), 256, 0, stream>>>(hfin, w3, b3, h3);
        gemm2<<<256, 256, 0, stream>>>(h3, l4_w, l4_b, out);
    } else {
        // fallback: device-atomic path (fits in ~42 MB)
        float* buf_msg  = (float*)(ws + 0);
        float* buf_deg  = (float*)(ws + (size_t)2097152);
        float* buf_a    = (float*)(ws + (size_t)4194304);
        float* buf_hfin = (float*)(ws + (size_t)6291456);
        float* buf_h3   = (float*)(ws + (size_t)8388608);
        float* buf_w3   = (float*)(ws + (size_t)41943040);
        float* buf_b3   = (float*)(ws + (size_t)42205184);

        hipMemsetAsync(buf_msg, 0, (size_t)N_NODES * 4, stream);
        hipMemsetAsync(buf_deg, 0, (size_t)N_NODES * 4, stream);
        fold_bn<<<256, 256, 0, stream>>>(l3_w, l3_b, bn_g, bn_b, buf_w3, buf_b3);
        edge_pass1<<<N_EDGES / 4 / 256, 256, 0, stream>>>(
            ei, ea, x, cg_wf, cg_bf, cg_ws, cg_bs, buf_msg, buf_deg);
        node_mid<<<N_NODES / 256, 256, 0, stream>>>(x, buf_msg, buf_deg, buf_a, gcn_w);
        hipMemsetAsync(buf_msg, 0, (size_t)N_NODES * 4, stream);
        edge_pass2<<<N_EDGES / 4 / 256, 256, 0, stream>>>(ei, ea, buf_a, buf_msg);
        node_fin<<<N_NODES / 256, 256, 0, stream>>>(buf_deg, buf_msg, gcn_b, buf_hfin);
        gemm1<<<dim3(16, 128), 256, 0, stream>>>(buf_hfin, buf_w3, buf_b3, buf_h3);
        gemm2<<<256, 256, 0, stream>>>(buf_h3, l4_w, l4_b, out);
    }
}